// Round 22
// baseline (147.716 us; speedup 1.0000x reference)
//
#include <hip/hip_runtime.h>

#define N_GRAPHS 64
#define EPB 8192          // edges per chunk in binning
#define BSTAGE 16384      // LDS staging capacity (records) in k_bprep
#define SROWSTRIDE 16384  // fixed per-bucket srow region (Poisson(8192), ~90-sigma safe)
#define PCHUNK 24         // pool chunks per graph in fused agg2+pool

#if __has_builtin(__builtin_amdgcn_cvt_pk_f32_fp8) && __has_builtin(__builtin_amdgcn_cvt_pk_fp8_f32)
#define HAS_FP8 1
#else
#define HAS_FP8 0
#endif

typedef float f32x2 __attribute__((ext_vector_type(2)));

// ---- bf16 helpers (manual, RNE) -------------------------------------------
__device__ inline float bf2f(unsigned short u) {
    union { unsigned u; float f; } c; c.u = (unsigned)u << 16; return c.f;
}
__device__ inline unsigned short f2bf(float f) {
    union { float f; unsigned u; } c; c.f = f;
    unsigned b = c.u;
    return (unsigned short)((b + 0x7fffu + ((b >> 16) & 1u)) >> 16);
}

// ---------------------------------------------------------------------------
// Chunk-local binning, single edge read: pack records+buckets into LDS,
// LDS histogram; in-LDS scan -> meta (chunk-major, coalesced); scatter FROM
// LDS into the chunk's own 32KB ebuf window.
__global__ __launch_bounds__(256) void k_count2(
        const int* __restrict__ row, const int* __restrict__ col,
        int* __restrict__ meta, unsigned int* __restrict__ ebuf,
        int E, int NBLK, int NBK) {
    __shared__ int h[512];
    __shared__ int scn[512];
    __shared__ unsigned recs[EPB];          // 32 KB packed records
    __shared__ unsigned short bucks[EPB];   // 16 KB bucket ids
    int t = threadIdx.x;
    int i0 = t, i1 = t + 256;
    h[i0] = 0; h[i1] = 0;
    __syncthreads();
    int s = blockIdx.x * EPB, e = min(E, s + EPB);
    int m = e - s;
    int nvec = m >> 2;
    const uint4* col4 = (const uint4*)(col + s);
    const uint4* row4 = (const uint4*)(row + s);
    for (int v = t; v < nvec; v += 256) {
        uint4 c = col4[v];
        uint4 r = row4[v];
        int j = v << 2;
        recs[j + 0] = (r.x << 8) | (c.x & 255u); bucks[j + 0] = (unsigned short)(c.x >> 8);
        recs[j + 1] = (r.y << 8) | (c.y & 255u); bucks[j + 1] = (unsigned short)(c.y >> 8);
        recs[j + 2] = (r.z << 8) | (c.z & 255u); bucks[j + 2] = (unsigned short)(c.z >> 8);
        recs[j + 3] = (r.w << 8) | (c.w & 255u); bucks[j + 3] = (unsigned short)(c.w >> 8);
        atomicAdd(&h[c.x >> 8], 1);
        atomicAdd(&h[c.y >> 8], 1);
        atomicAdd(&h[c.z >> 8], 1);
        atomicAdd(&h[c.w >> 8], 1);
    }
    for (int j = (nvec << 2) + t; j < m; j += 256) {
        unsigned c = (unsigned)col[s + j], r = (unsigned)row[s + j];
        recs[j] = (r << 8) | (c & 255u);
        bucks[j] = (unsigned short)(c >> 8);
        atomicAdd(&h[c >> 8], 1);
    }
    __syncthreads();
    scn[i0] = h[i0]; scn[i1] = h[i1];
    __syncthreads();
    for (int d = 1; d < 512; d <<= 1) {
        int v0 = (i0 >= d) ? scn[i0 - d] : 0;
        int v1 = (i1 >= d) ? scn[i1 - d] : 0;
        __syncthreads();
        scn[i0] += v0; scn[i1] += v1;
        __syncthreads();
    }
    int* mrow = meta + (size_t)blockIdx.x * NBK;
    if (i0 < NBK) { int c0 = h[i0], l0 = scn[i0] - c0; mrow[i0] = (l0 << 16) | c0; }
    if (i1 < NBK) { int c1 = h[i1], l1 = scn[i1] - c1; mrow[i1] = (l1 << 16) | c1; }
    __syncthreads();
    h[i0] = s + scn[i0] - h[i0];
    h[i1] = s + scn[i1] - h[i1];
    __syncthreads();
    for (int j = t; j < m; j += 256) {
        int p = atomicAdd(&h[bucks[j]], 1);
        ebuf[p] = recs[j];
    }
}

// Fused per-bucket CSR build: gather the bucket's chunk-segments into an LDS
// stage (+fused histogram) -> dinv/xs prep -> node scan -> off/oend -> srow
// into the bucket's FIXED region [b*SROWSTRIDE ...).
__global__ __launch_bounds__(256) void k_bprep(
        const unsigned int* __restrict__ ebuf, const int* __restrict__ meta,
        const float* __restrict__ x,
        float* __restrict__ dinv, unsigned short* __restrict__ xs,
        int* __restrict__ off, int* __restrict__ oend, int* __restrict__ srow,
        int n, int NBLK, int NBK) {
    __shared__ int h[256];
    __shared__ int cur[256];
    __shared__ int cnts[512];
    __shared__ int locs[512];
    __shared__ int scn[512];
    __shared__ unsigned stage[BSTAGE];   // 64 KB
    int t = threadIdx.x, b = blockIdx.x;
    int i0 = t, i1 = t + 256;
    h[t] = 0;
    cnts[i0] = 0; cnts[i1] = 0;
    __syncthreads();
    for (int k = t; k < NBLK; k += 256) {
        int m = meta[(size_t)k * NBK + b];
        cnts[k] = m & 0xffff;
        locs[k] = m >> 16;
    }
    __syncthreads();
    scn[i0] = cnts[i0]; scn[i1] = cnts[i1];
    __syncthreads();
    for (int d = 1; d < 512; d <<= 1) {
        int v0 = (i0 >= d) ? scn[i0 - d] : 0;
        int v1 = (i1 >= d) ? scn[i1 - d] : 0;
        __syncthreads();
        scn[i0] += v0; scn[i1] += v1;
        __syncthreads();
    }
    int mtot = scn[511];
    bool fit = (mtot <= BSTAGE);
    if (fit) {
        for (int k = t; k < NBLK; k += 256) {
            int cnt = cnts[k];
            const unsigned* src = ebuf + (size_t)k * EPB + locs[k];
            int dst = scn[k] - cnt;
            for (int q = 0; q < cnt; q++) {
                unsigned rec = src[q];
                stage[dst + q] = rec;
                atomicAdd(&h[rec & 255], 1);
            }
        }
    } else {
        for (int k = t; k < NBLK; k += 256) {
            int cnt = cnts[k];
            const unsigned* src = ebuf + (size_t)k * EPB + locs[k];
            for (int q = 0; q < cnt; q++)
                atomicAdd(&h[src[q] & 255], 1);
        }
    }
    __syncthreads();
    int dg = h[t];
    cur[t] = dg;
    __syncthreads();
    for (int d = 1; d < 256; d <<= 1) {
        int tmp = (t >= d) ? cur[t - d] : 0;
        __syncthreads();
        cur[t] += tmp;
        __syncthreads();
    }
    int base = b * SROWSTRIDE;
    int myoff = base + cur[t] - dg;   // exclusive offset in bucket's region
    int node = b * 256 + t;
    if (node < n) {
        off[node]  = myoff;
        oend[node] = myoff + dg;
        float d = rsqrtf((float)(dg + 1));
        dinv[node] = d;
        unsigned short r[8];
#pragma unroll
        for (int k = 0; k < 7; k++) r[k] = f2bf(x[(size_t)node * 7 + k] * d);
        r[7] = 0;
        uint4 v;
        v.x = (unsigned)r[0] | ((unsigned)r[1] << 16);
        v.y = (unsigned)r[2] | ((unsigned)r[3] << 16);
        v.z = (unsigned)r[4] | ((unsigned)r[5] << 16);
        v.w = (unsigned)r[6] | ((unsigned)r[7] << 16);
        *(uint4*)(xs + (size_t)node * 8) = v;
    }
    __syncthreads();
    cur[t] = myoff;                   // scatter cursors
    __syncthreads();
    if (fit) {
        for (int j = t; j < mtot; j += 256) {
            unsigned rec = stage[j];
            int p = atomicAdd(&cur[rec & 255], 1);
            srow[p] = (int)(rec >> 8);
        }
    } else {
        for (int k = t; k < NBLK; k += 256) {
            int cnt = cnts[k];
            const unsigned* src = ebuf + (size_t)k * EPB + locs[k];
            for (int q = 0; q < cnt; q++) {
                unsigned rec = src[q];
                int p = atomicAdd(&cur[rec & 255], 1);
                srow[p] = (int)(rec >> 8);
            }
        }
    }
}

// ---------------------------------------------------------------------------
// Layer-1 aggregation: QUAD per node. Lane fp owns 2 bf16 features; packed
// f32x2 accumulation, zero cross-lane ops.
__global__ __launch_bounds__(256) void k_agg1(
        const unsigned short* __restrict__ xs, const float* __restrict__ dinv,
        const int* __restrict__ off, const int* __restrict__ oend,
        const int* __restrict__ srow, float* __restrict__ aggx, int n) {
    int tid = blockIdx.x * blockDim.x + threadIdx.x;
    int c = tid >> 2;
    if (c >= n) return;
    int fp = tid & 3;
    int o0 = off[c], o1 = oend[c];
    f32x2 A = {0.f, 0.f};
    auto addp = [&](unsigned u) {
        union { unsigned x; float f; } lo, hi;
        lo.x = u << 16;
        hi.x = u & 0xffff0000u;
        f32x2 v; v.x = lo.f; v.y = hi.f;
        A += v;
    };
    addp(*(const unsigned*)(xs + (size_t)c * 8 + fp * 2));   // self loop
    int j = o0;
    for (; j + 4 <= o1; j += 4) {
        int r0 = srow[j], r1 = srow[j + 1], r2 = srow[j + 2], r3 = srow[j + 3];
        unsigned u0 = *(const unsigned*)(xs + (size_t)r0 * 8 + fp * 2);
        unsigned u1 = *(const unsigned*)(xs + (size_t)r1 * 8 + fp * 2);
        unsigned u2 = *(const unsigned*)(xs + (size_t)r2 * 8 + fp * 2);
        unsigned u3 = *(const unsigned*)(xs + (size_t)r3 * 8 + fp * 2);
        addp(u0); addp(u1); addp(u2); addp(u3);
    }
    for (; j < o1; j++)
        addp(*(const unsigned*)(xs + (size_t)srow[j] * 8 + fp * 2));
    float d = dinv[c];
    aggx[(size_t)c * 8 + fp * 2]     = A.x * d;
    aggx[(size_t)c * 8 + fp * 2 + 1] = A.y * d;
}

// Per node: h1 = relu(aggx @ W1 + b1); hs = (h1 @ W2) * dinv encoded as
// fp8 e4m3 x8 scale (32B row) if available, else bf16 (64B row).
// Also computes gstart from sorted batch.
__global__ __launch_bounds__(256) void k_mlp1(
        const float* __restrict__ aggx, const float* __restrict__ dinv,
        const float* __restrict__ W1, const float* __restrict__ b1,
        const float* __restrict__ W2,
        unsigned int* __restrict__ hs,
        const int* __restrict__ batch, int* __restrict__ gstart, int n) {
    __shared__ float sW1[7 * 64];
    __shared__ float sb1[64];
    __shared__ float sW2[64 * 32];
    for (int t = threadIdx.x; t < 7 * 64; t += blockDim.x) sW1[t] = W1[t];
    for (int t = threadIdx.x; t < 64; t += blockDim.x) sb1[t] = b1[t];
    for (int t = threadIdx.x; t < 64 * 32; t += blockDim.x) sW2[t] = W2[t];
    __syncthreads();

    int i = blockIdx.x * blockDim.x + threadIdx.x;
    if (i >= n) return;

    {   // graph start offsets (sorted batch, empty-graph safe)
        int g = batch[i];
        int gp = (i == 0) ? -1 : batch[i - 1];
        for (int q = gp + 1; q <= g; q++) gstart[q] = i;
        if (i == n - 1)
            for (int q = g + 1; q <= N_GRAPHS; q++) gstart[q] = n;
    }

    float a[7];
#pragma unroll
    for (int k = 0; k < 7; k++) a[k] = aggx[(size_t)i * 8 + k];

    float acc[32];
#pragma unroll
    for (int m = 0; m < 32; m++) acc[m] = 0.f;

    for (int j = 0; j < 64; j++) {
        float v = sb1[j];
#pragma unroll
        for (int k = 0; k < 7; k++) v += a[k] * sW1[k * 64 + j];
        v = fmaxf(v, 0.f);  // relu(conv1)
#pragma unroll
        for (int m = 0; m < 32; m++) acc[m] += v * sW2[j * 32 + m];
    }
    float d = dinv[i];
#if HAS_FP8
    float sc = d * 8.f;                 // fp8 scale = 8
    unsigned w[8];
#pragma unroll
    for (int q = 0; q < 8; q++) {
        unsigned t0 = (unsigned)__builtin_amdgcn_cvt_pk_fp8_f32(
            acc[4 * q] * sc, acc[4 * q + 1] * sc, 0, false);
        w[q] = (unsigned)__builtin_amdgcn_cvt_pk_fp8_f32(
            acc[4 * q + 2] * sc, acc[4 * q + 3] * sc, (int)t0, true);
    }
    uint4* o = (uint4*)(hs + (size_t)i * 8);
    o[0] = make_uint4(w[0], w[1], w[2], w[3]);
    o[1] = make_uint4(w[4], w[5], w[6], w[7]);
#else
    unsigned up[16];
#pragma unroll
    for (int m = 0; m < 16; m++)
        up[m] = (unsigned)f2bf(acc[2 * m] * d) |
                ((unsigned)f2bf(acc[2 * m + 1] * d) << 16);
    uint4* o = (uint4*)(hs + (size_t)i * 16);
    o[0] = make_uint4(up[0],  up[1],  up[2],  up[3]);
    o[1] = make_uint4(up[4],  up[5],  up[6],  up[7]);
    o[2] = make_uint4(up[8],  up[9],  up[10], up[11]);
    o[3] = make_uint4(up[12], up[13], up[14], up[15]);
#endif
}

// ---------------------------------------------------------------------------
// FUSED layer-2 aggregation + mean-pool partials. Grid = (graph, chunk):
// block (g, ch) owns a contiguous node slice of graph g. Each quad computes
// its nodes' agg2 rows in registers, applies relu(.+b2), accumulates pooled
// partials in registers; block-level reduce (shfl across 16 quads + LDS
// across 4 waves) -> ONE float4 store per 8 threads into private psum slot.
// agg2 is never materialized.
__global__ __launch_bounds__(256) void k_agg2p(
        const unsigned int* __restrict__ hs, const float* __restrict__ dinv,
        const int* __restrict__ off, const int* __restrict__ oend,
        const int* __restrict__ srow, const int* __restrict__ gstart,
        const float* __restrict__ b2, float* __restrict__ psum, int n) {
    int g = blockIdx.x / PCHUNK, ch = blockIdx.x % PCHUNK;
    int gs = gstart[g], ge = gstart[g + 1];
    int cnt = ge - gs;
    int per = (cnt + PCHUNK - 1) / PCHUNK;
    int cs = gs + ch * per, ce = min(ge, cs + per);

    int t = threadIdx.x;
    int q = t >> 2, fp = t & 3;
    float4 bq0 = *(const float4*)(b2 + fp * 8);
    float4 bq1 = *(const float4*)(b2 + fp * 8 + 4);
    f32x2 P0 = {0.f, 0.f}, P1 = {0.f, 0.f}, P2 = {0.f, 0.f}, P3 = {0.f, 0.f};

    for (int c = cs + q; c < ce; c += 64) {
        int o0 = off[c], o1 = oend[c];
#if HAS_FP8
        f32x2 A0 = {0.f, 0.f}, A1 = {0.f, 0.f}, A2 = {0.f, 0.f}, A3 = {0.f, 0.f};
        auto dec = [&](uint2 u) {
            A0 += __builtin_amdgcn_cvt_pk_f32_fp8((int)u.x, false);
            A1 += __builtin_amdgcn_cvt_pk_f32_fp8((int)u.x, true);
            A2 += __builtin_amdgcn_cvt_pk_f32_fp8((int)u.y, false);
            A3 += __builtin_amdgcn_cvt_pk_f32_fp8((int)u.y, true);
        };
        dec(*(const uint2*)(hs + (size_t)c * 8 + fp * 2));   // self loop
        int j = o0;
        for (; j + 4 <= o1; j += 4) {
            int r0 = srow[j], r1 = srow[j + 1], r2 = srow[j + 2], r3 = srow[j + 3];
            uint2 u0 = *(const uint2*)(hs + (size_t)r0 * 8 + fp * 2);
            uint2 u1 = *(const uint2*)(hs + (size_t)r1 * 8 + fp * 2);
            uint2 u2 = *(const uint2*)(hs + (size_t)r2 * 8 + fp * 2);
            uint2 u3 = *(const uint2*)(hs + (size_t)r3 * 8 + fp * 2);
            dec(u0); dec(u1); dec(u2); dec(u3);
        }
        for (; j < o1; j++)
            dec(*(const uint2*)(hs + (size_t)srow[j] * 8 + fp * 2));
        float d = dinv[c] * 0.125f;     // undo fp8 scale
#else
        f32x2 A0 = {0.f, 0.f}, A1 = {0.f, 0.f}, A2 = {0.f, 0.f}, A3 = {0.f, 0.f};
        auto addpair = [&](f32x2& X, unsigned u) {
            union { unsigned x; float f; } lo, hi;
            lo.x = u << 16; hi.x = u & 0xffff0000u;
            f32x2 v; v.x = lo.f; v.y = hi.f;
            X += v;
        };
        auto dec = [&](uint4 u) {
            addpair(A0, u.x); addpair(A1, u.y);
            addpair(A2, u.z); addpair(A3, u.w);
        };
        dec(*(const uint4*)(hs + (size_t)c * 16 + fp * 4));  // self loop
        int j = o0;
        for (; j + 4 <= o1; j += 4) {
            int r0 = srow[j], r1 = srow[j + 1], r2 = srow[j + 2], r3 = srow[j + 3];
            uint4 u0 = *(const uint4*)(hs + (size_t)r0 * 16 + fp * 4);
            uint4 u1 = *(const uint4*)(hs + (size_t)r1 * 16 + fp * 4);
            uint4 u2 = *(const uint4*)(hs + (size_t)r2 * 16 + fp * 4);
            uint4 u3 = *(const uint4*)(hs + (size_t)r3 * 16 + fp * 4);
            dec(u0); dec(u1); dec(u2); dec(u3);
        }
        for (; j < o1; j++)
            dec(*(const uint4*)(hs + (size_t)srow[j] * 16 + fp * 4));
        float d = dinv[c];
#endif
        P0.x += fmaxf(A0.x * d + bq0.x, 0.f);
        P0.y += fmaxf(A0.y * d + bq0.y, 0.f);
        P1.x += fmaxf(A1.x * d + bq0.z, 0.f);
        P1.y += fmaxf(A1.y * d + bq0.w, 0.f);
        P2.x += fmaxf(A2.x * d + bq1.x, 0.f);
        P2.y += fmaxf(A2.y * d + bq1.y, 0.f);
        P3.x += fmaxf(A3.x * d + bq1.z, 0.f);
        P3.y += fmaxf(A3.y * d + bq1.w, 0.f);
    }

    // reduce across 16 quads within each wave (fp stays fixed)
#pragma unroll
    for (int m = 4; m < 64; m <<= 1) {
        P0.x += __shfl_xor(P0.x, m); P0.y += __shfl_xor(P0.y, m);
        P1.x += __shfl_xor(P1.x, m); P1.y += __shfl_xor(P1.y, m);
        P2.x += __shfl_xor(P2.x, m); P2.y += __shfl_xor(P2.y, m);
        P3.x += __shfl_xor(P3.x, m); P3.y += __shfl_xor(P3.y, m);
    }
    __shared__ float4 part[4][4][2];
    int w = t >> 6, lane = t & 63;
    if (lane < 4) {
        part[w][lane][0] = make_float4(P0.x, P0.y, P1.x, P1.y);
        part[w][lane][1] = make_float4(P2.x, P2.y, P3.x, P3.y);
    }
    __syncthreads();
    if (t < 8) {
        int f = t & 3, hf = t >> 2;
        float4 s0 = part[0][f][hf], s1 = part[1][f][hf];
        float4 s2 = part[2][f][hf], s3 = part[3][f][hf];
        float4 r;
        r.x = s0.x + s1.x + s2.x + s3.x;
        r.y = s0.y + s1.y + s2.y + s3.y;
        r.z = s0.z + s1.z + s2.z + s3.z;
        r.w = s0.w + s1.w + s2.w + s3.w;
        *(float4*)(psum + ((size_t)(g * PCHUNK + ch)) * 32 + f * 8 + hf * 4) = r;
    }
}

// out[g][o] = (sum_m (sum_ch psum[g*PCHUNK+ch][m]) * Wl[m][o]) / max(cnt,1) + bl[o]
__global__ void k_out(const float* __restrict__ psum, const int* __restrict__ gstart,
                      const float* __restrict__ Wl, const float* __restrict__ bl,
                      float* __restrict__ out) {
    int t = blockIdx.x * blockDim.x + threadIdx.x;
    if (t >= N_GRAPHS * 5) return;
    int g = t / 5, o = t % 5;
    float c = (float)max(gstart[g + 1] - gstart[g], 1);
    float acc = 0.f;
#pragma unroll
    for (int m = 0; m < 32; m++) {
        float s = 0.f;
        for (int ch = 0; ch < PCHUNK; ch++)
            s += psum[((size_t)(g * PCHUNK + ch)) * 32 + m];
        acc += s * Wl[m * 5 + o];
    }
    out[t] = acc / c + bl[o];
}

extern "C" void kernel_launch(void* const* d_in, const int* in_sizes, int n_in,
                              void* d_out, int out_size, void* d_ws, size_t ws_size,
                              hipStream_t stream) {
    const float* x     = (const float*)d_in[0];
    const int*   ei    = (const int*)d_in[1];
    const int*   batch = (const int*)d_in[2];
    const float* W1    = (const float*)d_in[3];
    const float* b1    = (const float*)d_in[4];
    const float* W2    = (const float*)d_in[5];
    const float* b2    = (const float*)d_in[6];
    const float* Wl    = (const float*)d_in[7];
    const float* bl    = (const float*)d_in[8];
    float* out = (float*)d_out;

    const int n = in_sizes[0] / 7;        // 100000
    const int E = in_sizes[1] / 2;        // 3200000
    const int* row = ei;                  // edge_index[0]
    const int* col = ei + E;              // edge_index[1]

    const int NBK  = (n + 255) >> 8;              // 391 node-buckets
    const int NBLK = (E + EPB - 1) / EPB;         // 391 edge-chunks

    // workspace carve-up (256B aligned)
    char* p = (char*)d_ws;
    auto alloc = [&](size_t bytes) -> char* {
        char* r = p;
        p += (bytes + 255) & ~(size_t)255;
        return r;
    };
    int*   meta   = (int*)  alloc((size_t)NBLK * NBK * 4);          // 612 KB
    unsigned int* ebuf = (unsigned int*)alloc((size_t)E * 4);
    int*   srow   = (int*)  alloc((size_t)NBK * SROWSTRIDE * 4);    // 25.6 MB
    float* dinv   = (float*)alloc((size_t)n * 4);
    int*   off    = (int*)  alloc((size_t)n * 4);
    int*   oendv  = (int*)  alloc((size_t)n * 4);
    unsigned short* xs = (unsigned short*)alloc((size_t)n * 8 * 2);
    float* aggx   = (float*)alloc((size_t)n * 8 * 4);
    unsigned int* hs = (unsigned int*)alloc((size_t)n * 16 * 4);    // max (bf16) size
    int*   gstart = (int*)  alloc((N_GRAPHS + 1) * 4);
    float* psum   = (float*)alloc((size_t)N_GRAPHS * PCHUNK * 32 * 4);

    const int BT = 256;
    int nb_n    = (n + BT - 1) / BT;
    int nb_quad = (n * 4 + BT - 1) / BT;          // one quad (4 lanes) per node

    // chunk-local binned CSR build (single edge read, fixed bucket regions)
    k_count2 <<<NBLK, BT, 0, stream>>>(row, col, meta, ebuf, E, NBLK, NBK);
    k_bprep  <<<NBK, BT, 0, stream>>>(ebuf, meta, x, dinv, xs, off, oendv, srow,
                                      n, NBLK, NBK);

    // GNN pipeline (quad-per-node gathers; fused agg2+pool)
    k_agg1   <<<nb_quad, BT, 0, stream>>>(xs, dinv, off, oendv, srow, aggx, n);
    k_mlp1   <<<nb_n, BT, 0, stream>>>(aggx, dinv, W1, b1, W2, hs, batch, gstart, n);
    k_agg2p  <<<N_GRAPHS * PCHUNK, BT, 0, stream>>>(hs, dinv, off, oendv, srow,
                                                    gstart, b2, psum, n);
    k_out    <<<1, 320, 0, stream>>>(psum, gstart, Wl, bl, out);
}

// Round 23
// 138.136 us; speedup vs baseline: 1.0694x; 1.0694x over previous
//
#include <hip/hip_runtime.h>

#define N_GRAPHS 64
#define EPB 8192          // edges per chunk in binning
#define BSTAGE 16384      // LDS staging capacity (records) in k_bprep
#define SROWSTRIDE 16384  // fixed per-bucket srow region (Poisson(8192), ~90-sigma safe)

#if __has_builtin(__builtin_amdgcn_cvt_pk_f32_fp8) && __has_builtin(__builtin_amdgcn_cvt_pk_fp8_f32)
#define HAS_FP8 1
#else
#define HAS_FP8 0
#endif

typedef float f32x2 __attribute__((ext_vector_type(2)));

// ---- bf16 helpers (manual, RNE) -------------------------------------------
__device__ inline float bf2f(unsigned short u) {
    union { unsigned u; float f; } c; c.u = (unsigned)u << 16; return c.f;
}
__device__ inline unsigned short f2bf(float f) {
    union { float f; unsigned u; } c; c.f = f;
    unsigned b = c.u;
    return (unsigned short)((b + 0x7fffu + ((b >> 16) & 1u)) >> 16);
}

// ---------------------------------------------------------------------------
// Chunk-local binning, single edge read: pack records+buckets into LDS,
// LDS histogram; in-LDS scan -> meta (chunk-major, coalesced); scatter FROM
// LDS into the chunk's own 32KB ebuf window.
__global__ __launch_bounds__(256) void k_count2(
        const int* __restrict__ row, const int* __restrict__ col,
        int* __restrict__ meta, unsigned int* __restrict__ ebuf,
        int E, int NBLK, int NBK) {
    __shared__ int h[512];
    __shared__ int scn[512];
    __shared__ unsigned recs[EPB];          // 32 KB packed records
    __shared__ unsigned short bucks[EPB];   // 16 KB bucket ids
    int t = threadIdx.x;
    int i0 = t, i1 = t + 256;
    h[i0] = 0; h[i1] = 0;
    __syncthreads();
    int s = blockIdx.x * EPB, e = min(E, s + EPB);
    int m = e - s;
    int nvec = m >> 2;
    const uint4* col4 = (const uint4*)(col + s);
    const uint4* row4 = (const uint4*)(row + s);
    for (int v = t; v < nvec; v += 256) {
        uint4 c = col4[v];
        uint4 r = row4[v];
        int j = v << 2;
        recs[j + 0] = (r.x << 8) | (c.x & 255u); bucks[j + 0] = (unsigned short)(c.x >> 8);
        recs[j + 1] = (r.y << 8) | (c.y & 255u); bucks[j + 1] = (unsigned short)(c.y >> 8);
        recs[j + 2] = (r.z << 8) | (c.z & 255u); bucks[j + 2] = (unsigned short)(c.z >> 8);
        recs[j + 3] = (r.w << 8) | (c.w & 255u); bucks[j + 3] = (unsigned short)(c.w >> 8);
        atomicAdd(&h[c.x >> 8], 1);
        atomicAdd(&h[c.y >> 8], 1);
        atomicAdd(&h[c.z >> 8], 1);
        atomicAdd(&h[c.w >> 8], 1);
    }
    for (int j = (nvec << 2) + t; j < m; j += 256) {
        unsigned c = (unsigned)col[s + j], r = (unsigned)row[s + j];
        recs[j] = (r << 8) | (c & 255u);
        bucks[j] = (unsigned short)(c >> 8);
        atomicAdd(&h[c >> 8], 1);
    }
    __syncthreads();
    scn[i0] = h[i0]; scn[i1] = h[i1];
    __syncthreads();
    for (int d = 1; d < 512; d <<= 1) {
        int v0 = (i0 >= d) ? scn[i0 - d] : 0;
        int v1 = (i1 >= d) ? scn[i1 - d] : 0;
        __syncthreads();
        scn[i0] += v0; scn[i1] += v1;
        __syncthreads();
    }
    int* mrow = meta + (size_t)blockIdx.x * NBK;
    if (i0 < NBK) { int c0 = h[i0], l0 = scn[i0] - c0; mrow[i0] = (l0 << 16) | c0; }
    if (i1 < NBK) { int c1 = h[i1], l1 = scn[i1] - c1; mrow[i1] = (l1 << 16) | c1; }
    __syncthreads();
    h[i0] = s + scn[i0] - h[i0];
    h[i1] = s + scn[i1] - h[i1];
    __syncthreads();
    for (int j = t; j < m; j += 256) {
        int p = atomicAdd(&h[bucks[j]], 1);
        ebuf[p] = recs[j];
    }
}

// Fused per-bucket CSR build: gather the bucket's chunk-segments into an LDS
// stage (+fused histogram) -> dinv/xs prep -> node scan -> off/oend -> srow
// into the bucket's FIXED region [b*SROWSTRIDE ...).
__global__ __launch_bounds__(256) void k_bprep(
        const unsigned int* __restrict__ ebuf, const int* __restrict__ meta,
        const float* __restrict__ x,
        float* __restrict__ dinv, unsigned short* __restrict__ xs,
        int* __restrict__ off, int* __restrict__ oend, int* __restrict__ srow,
        int n, int NBLK, int NBK) {
    __shared__ int h[256];
    __shared__ int cur[256];
    __shared__ int cnts[512];
    __shared__ int locs[512];
    __shared__ int scn[512];
    __shared__ unsigned stage[BSTAGE];   // 64 KB
    int t = threadIdx.x, b = blockIdx.x;
    int i0 = t, i1 = t + 256;
    h[t] = 0;
    cnts[i0] = 0; cnts[i1] = 0;
    __syncthreads();
    for (int k = t; k < NBLK; k += 256) {
        int m = meta[(size_t)k * NBK + b];
        cnts[k] = m & 0xffff;
        locs[k] = m >> 16;
    }
    __syncthreads();
    scn[i0] = cnts[i0]; scn[i1] = cnts[i1];
    __syncthreads();
    for (int d = 1; d < 512; d <<= 1) {
        int v0 = (i0 >= d) ? scn[i0 - d] : 0;
        int v1 = (i1 >= d) ? scn[i1 - d] : 0;
        __syncthreads();
        scn[i0] += v0; scn[i1] += v1;
        __syncthreads();
    }
    int mtot = scn[511];
    bool fit = (mtot <= BSTAGE);
    if (fit) {
        for (int k = t; k < NBLK; k += 256) {
            int cnt = cnts[k];
            const unsigned* src = ebuf + (size_t)k * EPB + locs[k];
            int dst = scn[k] - cnt;
            for (int q = 0; q < cnt; q++) {
                unsigned rec = src[q];
                stage[dst + q] = rec;
                atomicAdd(&h[rec & 255], 1);
            }
        }
    } else {
        for (int k = t; k < NBLK; k += 256) {
            int cnt = cnts[k];
            const unsigned* src = ebuf + (size_t)k * EPB + locs[k];
            for (int q = 0; q < cnt; q++)
                atomicAdd(&h[src[q] & 255], 1);
        }
    }
    __syncthreads();
    int dg = h[t];
    cur[t] = dg;
    __syncthreads();
    for (int d = 1; d < 256; d <<= 1) {
        int tmp = (t >= d) ? cur[t - d] : 0;
        __syncthreads();
        cur[t] += tmp;
        __syncthreads();
    }
    int base = b * SROWSTRIDE;
    int myoff = base + cur[t] - dg;   // exclusive offset in bucket's region
    int node = b * 256 + t;
    if (node < n) {
        off[node]  = myoff;
        oend[node] = myoff + dg;
        float d = rsqrtf((float)(dg + 1));
        dinv[node] = d;
        unsigned short r[8];
#pragma unroll
        for (int k = 0; k < 7; k++) r[k] = f2bf(x[(size_t)node * 7 + k] * d);
        r[7] = 0;
        uint4 v;
        v.x = (unsigned)r[0] | ((unsigned)r[1] << 16);
        v.y = (unsigned)r[2] | ((unsigned)r[3] << 16);
        v.z = (unsigned)r[4] | ((unsigned)r[5] << 16);
        v.w = (unsigned)r[6] | ((unsigned)r[7] << 16);
        *(uint4*)(xs + (size_t)node * 8) = v;
    }
    __syncthreads();
    cur[t] = myoff;                   // scatter cursors
    __syncthreads();
    if (fit) {
        for (int j = t; j < mtot; j += 256) {
            unsigned rec = stage[j];
            int p = atomicAdd(&cur[rec & 255], 1);
            srow[p] = (int)(rec >> 8);
        }
    } else {
        for (int k = t; k < NBLK; k += 256) {
            int cnt = cnts[k];
            const unsigned* src = ebuf + (size_t)k * EPB + locs[k];
            for (int q = 0; q < cnt; q++) {
                unsigned rec = src[q];
                int p = atomicAdd(&cur[rec & 255], 1);
                srow[p] = (int)(rec >> 8);
            }
        }
    }
}

// ---------------------------------------------------------------------------
// Layer-1 aggregation: QUAD per node. Lane fp owns 2 bf16 features; packed
// f32x2 accumulation, zero cross-lane ops.
__global__ __launch_bounds__(256) void k_agg1(
        const unsigned short* __restrict__ xs, const float* __restrict__ dinv,
        const int* __restrict__ off, const int* __restrict__ oend,
        const int* __restrict__ srow, float* __restrict__ aggx, int n) {
    int tid = blockIdx.x * blockDim.x + threadIdx.x;
    int c = tid >> 2;
    if (c >= n) return;
    int fp = tid & 3;
    int o0 = off[c], o1 = oend[c];
    f32x2 A = {0.f, 0.f};
    auto addp = [&](unsigned u) {
        union { unsigned x; float f; } lo, hi;
        lo.x = u << 16;
        hi.x = u & 0xffff0000u;
        f32x2 v; v.x = lo.f; v.y = hi.f;
        A += v;
    };
    addp(*(const unsigned*)(xs + (size_t)c * 8 + fp * 2));   // self loop
    int j = o0;
    for (; j + 4 <= o1; j += 4) {
        int r0 = srow[j], r1 = srow[j + 1], r2 = srow[j + 2], r3 = srow[j + 3];
        unsigned u0 = *(const unsigned*)(xs + (size_t)r0 * 8 + fp * 2);
        unsigned u1 = *(const unsigned*)(xs + (size_t)r1 * 8 + fp * 2);
        unsigned u2 = *(const unsigned*)(xs + (size_t)r2 * 8 + fp * 2);
        unsigned u3 = *(const unsigned*)(xs + (size_t)r3 * 8 + fp * 2);
        addp(u0); addp(u1); addp(u2); addp(u3);
    }
    for (; j < o1; j++)
        addp(*(const unsigned*)(xs + (size_t)srow[j] * 8 + fp * 2));
    float d = dinv[c];
    aggx[(size_t)c * 8 + fp * 2]     = A.x * d;
    aggx[(size_t)c * 8 + fp * 2 + 1] = A.y * d;
}

// Per node: h1 = relu(aggx @ W1 + b1); hs = (h1 @ W2) * dinv encoded as
// fp8 e4m3 x8 scale (32B row) if available, else bf16 (64B row).
// Also computes gstart from sorted batch.
__global__ __launch_bounds__(256) void k_mlp1(
        const float* __restrict__ aggx, const float* __restrict__ dinv,
        const float* __restrict__ W1, const float* __restrict__ b1,
        const float* __restrict__ W2,
        unsigned int* __restrict__ hs,
        const int* __restrict__ batch, int* __restrict__ gstart, int n) {
    __shared__ float sW1[7 * 64];
    __shared__ float sb1[64];
    __shared__ float sW2[64 * 32];
    for (int t = threadIdx.x; t < 7 * 64; t += blockDim.x) sW1[t] = W1[t];
    for (int t = threadIdx.x; t < 64; t += blockDim.x) sb1[t] = b1[t];
    for (int t = threadIdx.x; t < 64 * 32; t += blockDim.x) sW2[t] = W2[t];
    __syncthreads();

    int i = blockIdx.x * blockDim.x + threadIdx.x;
    if (i >= n) return;

    {   // graph start offsets (sorted batch, empty-graph safe)
        int g = batch[i];
        int gp = (i == 0) ? -1 : batch[i - 1];
        for (int q = gp + 1; q <= g; q++) gstart[q] = i;
        if (i == n - 1)
            for (int q = g + 1; q <= N_GRAPHS; q++) gstart[q] = n;
    }

    float a[7];
#pragma unroll
    for (int k = 0; k < 7; k++) a[k] = aggx[(size_t)i * 8 + k];

    float acc[32];
#pragma unroll
    for (int m = 0; m < 32; m++) acc[m] = 0.f;

    for (int j = 0; j < 64; j++) {
        float v = sb1[j];
#pragma unroll
        for (int k = 0; k < 7; k++) v += a[k] * sW1[k * 64 + j];
        v = fmaxf(v, 0.f);  // relu(conv1)
#pragma unroll
        for (int m = 0; m < 32; m++) acc[m] += v * sW2[j * 32 + m];
    }
    float d = dinv[i];
#if HAS_FP8
    float sc = d * 8.f;                 // fp8 scale = 8
    unsigned w[8];
#pragma unroll
    for (int q = 0; q < 8; q++) {
        unsigned t0 = (unsigned)__builtin_amdgcn_cvt_pk_fp8_f32(
            acc[4 * q] * sc, acc[4 * q + 1] * sc, 0, false);
        w[q] = (unsigned)__builtin_amdgcn_cvt_pk_fp8_f32(
            acc[4 * q + 2] * sc, acc[4 * q + 3] * sc, (int)t0, true);
    }
    uint4* o = (uint4*)(hs + (size_t)i * 8);
    o[0] = make_uint4(w[0], w[1], w[2], w[3]);
    o[1] = make_uint4(w[4], w[5], w[6], w[7]);
#else
    unsigned up[16];
#pragma unroll
    for (int m = 0; m < 16; m++)
        up[m] = (unsigned)f2bf(acc[2 * m] * d) |
                ((unsigned)f2bf(acc[2 * m + 1] * d) << 16);
    uint4* o = (uint4*)(hs + (size_t)i * 16);
    o[0] = make_uint4(up[0],  up[1],  up[2],  up[3]);
    o[1] = make_uint4(up[4],  up[5],  up[6],  up[7]);
    o[2] = make_uint4(up[8],  up[9],  up[10], up[11]);
    o[3] = make_uint4(up[12], up[13], up[14], up[15]);
#endif
}

// Layer-2 aggregation: QUAD per node. Lane fp owns 8 fp8 features (uint2);
// packed f32x2 accumulation; gather loop unrolled 8x (8 loads in flight per
// lane -> ~4 dependent rounds for the median deg-32 node).
__global__ __launch_bounds__(256) void k_agg2(
        const unsigned int* __restrict__ hs, const float* __restrict__ dinv,
        const int* __restrict__ off, const int* __restrict__ oend,
        const int* __restrict__ srow, float* __restrict__ agg2, int n) {
    int tid = blockIdx.x * blockDim.x + threadIdx.x;
    int c = tid >> 2;
    if (c >= n) return;
    int fp = tid & 3;
    int o0 = off[c], o1 = oend[c];
#if HAS_FP8
    f32x2 A0 = {0.f, 0.f}, A1 = {0.f, 0.f}, A2 = {0.f, 0.f}, A3 = {0.f, 0.f};
    auto dec = [&](uint2 u) {
        A0 += __builtin_amdgcn_cvt_pk_f32_fp8((int)u.x, false);
        A1 += __builtin_amdgcn_cvt_pk_f32_fp8((int)u.x, true);
        A2 += __builtin_amdgcn_cvt_pk_f32_fp8((int)u.y, false);
        A3 += __builtin_amdgcn_cvt_pk_f32_fp8((int)u.y, true);
    };
    dec(*(const uint2*)(hs + (size_t)c * 8 + fp * 2));   // self loop
    int j = o0;
    for (; j + 8 <= o1; j += 8) {
        int r0 = srow[j],     r1 = srow[j + 1], r2 = srow[j + 2], r3 = srow[j + 3];
        int r4 = srow[j + 4], r5 = srow[j + 5], r6 = srow[j + 6], r7 = srow[j + 7];
        uint2 u0 = *(const uint2*)(hs + (size_t)r0 * 8 + fp * 2);
        uint2 u1 = *(const uint2*)(hs + (size_t)r1 * 8 + fp * 2);
        uint2 u2 = *(const uint2*)(hs + (size_t)r2 * 8 + fp * 2);
        uint2 u3 = *(const uint2*)(hs + (size_t)r3 * 8 + fp * 2);
        uint2 u4 = *(const uint2*)(hs + (size_t)r4 * 8 + fp * 2);
        uint2 u5 = *(const uint2*)(hs + (size_t)r5 * 8 + fp * 2);
        uint2 u6 = *(const uint2*)(hs + (size_t)r6 * 8 + fp * 2);
        uint2 u7 = *(const uint2*)(hs + (size_t)r7 * 8 + fp * 2);
        dec(u0); dec(u1); dec(u2); dec(u3);
        dec(u4); dec(u5); dec(u6); dec(u7);
    }
    for (; j + 4 <= o1; j += 4) {
        int r0 = srow[j], r1 = srow[j + 1], r2 = srow[j + 2], r3 = srow[j + 3];
        uint2 u0 = *(const uint2*)(hs + (size_t)r0 * 8 + fp * 2);
        uint2 u1 = *(const uint2*)(hs + (size_t)r1 * 8 + fp * 2);
        uint2 u2 = *(const uint2*)(hs + (size_t)r2 * 8 + fp * 2);
        uint2 u3 = *(const uint2*)(hs + (size_t)r3 * 8 + fp * 2);
        dec(u0); dec(u1); dec(u2); dec(u3);
    }
    for (; j < o1; j++)
        dec(*(const uint2*)(hs + (size_t)srow[j] * 8 + fp * 2));
    float d = dinv[c] * 0.125f;     // undo fp8 scale
    float4* o = (float4*)(agg2 + (size_t)c * 32 + fp * 8);
    o[0] = make_float4(A0.x * d, A0.y * d, A1.x * d, A1.y * d);
    o[1] = make_float4(A2.x * d, A2.y * d, A3.x * d, A3.y * d);
#else
    float a0 = 0.f, a1 = 0.f, a2 = 0.f, a3 = 0.f;
    float a4 = 0.f, a5 = 0.f, a6 = 0.f, a7 = 0.f;
    auto addpair = [&](float& x0, float& x1, unsigned u) {
        union { unsigned x; float f; } lo, hi;
        lo.x = u << 16; hi.x = u & 0xffff0000u;
        x0 += lo.f; x1 += hi.f;
    };
    auto dec = [&](uint4 u) {
        addpair(a0, a1, u.x); addpair(a2, a3, u.y);
        addpair(a4, a5, u.z); addpair(a6, a7, u.w);
    };
    dec(*(const uint4*)(hs + (size_t)c * 16 + fp * 4));  // self loop
    int j = o0;
    for (; j + 4 <= o1; j += 4) {
        int r0 = srow[j], r1 = srow[j + 1], r2 = srow[j + 2], r3 = srow[j + 3];
        uint4 u0 = *(const uint4*)(hs + (size_t)r0 * 16 + fp * 4);
        uint4 u1 = *(const uint4*)(hs + (size_t)r1 * 16 + fp * 4);
        uint4 u2 = *(const uint4*)(hs + (size_t)r2 * 16 + fp * 4);
        uint4 u3 = *(const uint4*)(hs + (size_t)r3 * 16 + fp * 4);
        dec(u0); dec(u1); dec(u2); dec(u3);
    }
    for (; j < o1; j++)
        dec(*(const uint4*)(hs + (size_t)srow[j] * 16 + fp * 4));
    float d = dinv[c];
    float4* o = (float4*)(agg2 + (size_t)c * 32 + fp * 8);
    o[0] = make_float4(a0 * d, a1 * d, a2 * d, a3 * d);
    o[1] = make_float4(a4 * d, a5 * d, a6 * d, a7 * d);
#endif
}

// ---------------------------------------------------------------------------
// Mean-pool partials: 8 chunk-blocks per graph; private slots, no atomics.
__global__ __launch_bounds__(256) void k_pool(
        const float* __restrict__ agg2, const float* __restrict__ b2,
        const int* __restrict__ gstart, float* __restrict__ psum) {
    int g = blockIdx.x >> 3, ch = blockIdx.x & 7;
    int s = gstart[g], e = gstart[g + 1];
    int cnt = e - s;
    int per = (cnt + 7) >> 3;
    int cs = s + ch * per, ce = min(e, cs + per);

    int t = threadIdx.x;
    int fq = t & 7, nl = t >> 3;
    const float4* b2q4 = (const float4*)b2;
    float4 bq = b2q4[fq];
    float4 acc = make_float4(0.f, 0.f, 0.f, 0.f);
    for (int i = cs + nl; i < ce; i += 32) {
        float4 v = *(const float4*)(agg2 + (size_t)i * 32 + fq * 4);
        acc.x += fmaxf(v.x + bq.x, 0.f);
        acc.y += fmaxf(v.y + bq.y, 0.f);
        acc.z += fmaxf(v.z + bq.z, 0.f);
        acc.w += fmaxf(v.w + bq.w, 0.f);
    }
#pragma unroll
    for (int m = 8; m < 64; m <<= 1) {
        acc.x += __shfl_xor(acc.x, m);
        acc.y += __shfl_xor(acc.y, m);
        acc.z += __shfl_xor(acc.z, m);
        acc.w += __shfl_xor(acc.w, m);
    }
    __shared__ float4 part[4][8];
    int w = t >> 6, lane = t & 63;
    if (lane < 8) part[w][lane] = acc;
    __syncthreads();
    if (t < 8) {
        float4 p0 = part[0][t], p1 = part[1][t], p2 = part[2][t], p3 = part[3][t];
        float4 r;
        r.x = p0.x + p1.x + p2.x + p3.x;
        r.y = p0.y + p1.y + p2.y + p3.y;
        r.z = p0.z + p1.z + p2.z + p3.z;
        r.w = p0.w + p1.w + p2.w + p3.w;
        *(float4*)(psum + ((size_t)((g << 3) + ch)) * 32 + t * 4) = r;
    }
}

// out[g][o] = (sum_m (sum_ch psum[g*8+ch][m]) * Wl[m][o]) / max(cnt,1) + bl[o]
__global__ void k_out(const float* __restrict__ psum, const int* __restrict__ gstart,
                      const float* __restrict__ Wl, const float* __restrict__ bl,
                      float* __restrict__ out) {
    int t = blockIdx.x * blockDim.x + threadIdx.x;
    if (t >= N_GRAPHS * 5) return;
    int g = t / 5, o = t % 5;
    float c = (float)max(gstart[g + 1] - gstart[g], 1);
    float acc = 0.f;
#pragma unroll
    for (int m = 0; m < 32; m++) {
        float s = 0.f;
#pragma unroll
        for (int ch = 0; ch < 8; ch++)
            s += psum[((size_t)((g << 3) + ch)) * 32 + m];
        acc += s * Wl[m * 5 + o];
    }
    out[t] = acc / c + bl[o];
}

extern "C" void kernel_launch(void* const* d_in, const int* in_sizes, int n_in,
                              void* d_out, int out_size, void* d_ws, size_t ws_size,
                              hipStream_t stream) {
    const float* x     = (const float*)d_in[0];
    const int*   ei    = (const int*)d_in[1];
    const int*   batch = (const int*)d_in[2];
    const float* W1    = (const float*)d_in[3];
    const float* b1    = (const float*)d_in[4];
    const float* W2    = (const float*)d_in[5];
    const float* b2    = (const float*)d_in[6];
    const float* Wl    = (const float*)d_in[7];
    const float* bl    = (const float*)d_in[8];
    float* out = (float*)d_out;

    const int n = in_sizes[0] / 7;        // 100000
    const int E = in_sizes[1] / 2;        // 3200000
    const int* row = ei;                  // edge_index[0]
    const int* col = ei + E;              // edge_index[1]

    const int NBK  = (n + 255) >> 8;              // 391 node-buckets
    const int NBLK = (E + EPB - 1) / EPB;         // 391 edge-chunks

    // workspace carve-up (256B aligned)
    char* p = (char*)d_ws;
    auto alloc = [&](size_t bytes) -> char* {
        char* r = p;
        p += (bytes + 255) & ~(size_t)255;
        return r;
    };
    int*   meta   = (int*)  alloc((size_t)NBLK * NBK * 4);          // 612 KB
    unsigned int* ebuf = (unsigned int*)alloc((size_t)E * 4);
    int*   srow   = (int*)  alloc((size_t)NBK * SROWSTRIDE * 4);    // 25.6 MB
    float* dinv   = (float*)alloc((size_t)n * 4);
    int*   off    = (int*)  alloc((size_t)n * 4);
    int*   oendv  = (int*)  alloc((size_t)n * 4);
    unsigned short* xs = (unsigned short*)alloc((size_t)n * 8 * 2);
    float* aggx   = (float*)alloc((size_t)n * 8 * 4);
    unsigned int* hs = (unsigned int*)alloc((size_t)n * 16 * 4);    // max (bf16) size
    float* agg2   = (float*)alloc((size_t)n * 32 * 4);
    int*   gstart = (int*)  alloc((N_GRAPHS + 1) * 4);
    float* psum   = (float*)alloc((size_t)N_GRAPHS * 8 * 32 * 4);

    const int BT = 256;
    int nb_n    = (n + BT - 1) / BT;
    int nb_quad = (n * 4 + BT - 1) / BT;          // one quad (4 lanes) per node

    // chunk-local binned CSR build (single edge read, fixed bucket regions)
    k_count2 <<<NBLK, BT, 0, stream>>>(row, col, meta, ebuf, E, NBLK, NBK);
    k_bprep  <<<NBK, BT, 0, stream>>>(ebuf, meta, x, dinv, xs, off, oendv, srow,
                                      n, NBLK, NBK);

    // GNN pipeline (quad-per-node gathers, packed-f32 accumulation)
    k_agg1   <<<nb_quad, BT, 0, stream>>>(xs, dinv, off, oendv, srow, aggx, n);
    k_mlp1   <<<nb_n, BT, 0, stream>>>(aggx, dinv, W1, b1, W2, hs, batch, gstart, n);
    k_agg2   <<<nb_quad, BT, 0, stream>>>(hs, dinv, off, oendv, srow, agg2, n);
    k_pool   <<<N_GRAPHS * 8, BT, 0, stream>>>(agg2, b2, gstart, psum);
    k_out    <<<1, 320, 0, stream>>>(psum, gstart, Wl, bl, out);
}

// Round 24
// 136.113 us; speedup vs baseline: 1.0852x; 1.0149x over previous
//
#include <hip/hip_runtime.h>

#define N_GRAPHS 64
#define EPB 8192          // edges per chunk in binning
#define BSTAGE 16384      // LDS staging capacity (records) in k_bprep
#define SROWSTRIDE 16384  // fixed per-bucket srow region (Poisson(8192), ~90-sigma safe)

#if __has_builtin(__builtin_amdgcn_cvt_pk_f32_fp8) && __has_builtin(__builtin_amdgcn_cvt_pk_fp8_f32)
#define HAS_FP8 1
#else
#define HAS_FP8 0
#endif

typedef float f32x2 __attribute__((ext_vector_type(2)));

// ---- bf16 helpers (manual, RNE) -------------------------------------------
__device__ inline float bf2f(unsigned short u) {
    union { unsigned u; float f; } c; c.u = (unsigned)u << 16; return c.f;
}
__device__ inline unsigned short f2bf(float f) {
    union { float f; unsigned u; } c; c.f = f;
    unsigned b = c.u;
    return (unsigned short)((b + 0x7fffu + ((b >> 16) & 1u)) >> 16);
}

// ---------------------------------------------------------------------------
// Chunk-local binning, single edge read: pack records+buckets into LDS,
// LDS histogram; in-LDS scan -> meta (chunk-major, coalesced); scatter FROM
// LDS into the chunk's own 32KB ebuf window.
__global__ __launch_bounds__(256) void k_count2(
        const int* __restrict__ row, const int* __restrict__ col,
        int* __restrict__ meta, unsigned int* __restrict__ ebuf,
        int E, int NBLK, int NBK) {
    __shared__ int h[512];
    __shared__ int scn[512];
    __shared__ unsigned recs[EPB];          // 32 KB packed records
    __shared__ unsigned short bucks[EPB];   // 16 KB bucket ids
    int t = threadIdx.x;
    int i0 = t, i1 = t + 256;
    h[i0] = 0; h[i1] = 0;
    __syncthreads();
    int s = blockIdx.x * EPB, e = min(E, s + EPB);
    int m = e - s;
    int nvec = m >> 2;
    const uint4* col4 = (const uint4*)(col + s);
    const uint4* row4 = (const uint4*)(row + s);
    for (int v = t; v < nvec; v += 256) {
        uint4 c = col4[v];
        uint4 r = row4[v];
        int j = v << 2;
        recs[j + 0] = (r.x << 8) | (c.x & 255u); bucks[j + 0] = (unsigned short)(c.x >> 8);
        recs[j + 1] = (r.y << 8) | (c.y & 255u); bucks[j + 1] = (unsigned short)(c.y >> 8);
        recs[j + 2] = (r.z << 8) | (c.z & 255u); bucks[j + 2] = (unsigned short)(c.z >> 8);
        recs[j + 3] = (r.w << 8) | (c.w & 255u); bucks[j + 3] = (unsigned short)(c.w >> 8);
        atomicAdd(&h[c.x >> 8], 1);
        atomicAdd(&h[c.y >> 8], 1);
        atomicAdd(&h[c.z >> 8], 1);
        atomicAdd(&h[c.w >> 8], 1);
    }
    for (int j = (nvec << 2) + t; j < m; j += 256) {
        unsigned c = (unsigned)col[s + j], r = (unsigned)row[s + j];
        recs[j] = (r << 8) | (c & 255u);
        bucks[j] = (unsigned short)(c >> 8);
        atomicAdd(&h[c >> 8], 1);
    }
    __syncthreads();
    scn[i0] = h[i0]; scn[i1] = h[i1];
    __syncthreads();
    for (int d = 1; d < 512; d <<= 1) {
        int v0 = (i0 >= d) ? scn[i0 - d] : 0;
        int v1 = (i1 >= d) ? scn[i1 - d] : 0;
        __syncthreads();
        scn[i0] += v0; scn[i1] += v1;
        __syncthreads();
    }
    int* mrow = meta + (size_t)blockIdx.x * NBK;
    if (i0 < NBK) { int c0 = h[i0], l0 = scn[i0] - c0; mrow[i0] = (l0 << 16) | c0; }
    if (i1 < NBK) { int c1 = h[i1], l1 = scn[i1] - c1; mrow[i1] = (l1 << 16) | c1; }
    __syncthreads();
    h[i0] = s + scn[i0] - h[i0];
    h[i1] = s + scn[i1] - h[i1];
    __syncthreads();
    for (int j = t; j < m; j += 256) {
        int p = atomicAdd(&h[bucks[j]], 1);
        ebuf[p] = recs[j];
    }
}

// Fused per-bucket CSR build: gather the bucket's chunk-segments into an LDS
// stage (+fused histogram) -> dinv/xs prep -> node scan -> off/oend -> srow
// into the bucket's FIXED region [b*SROWSTRIDE ...).
__global__ __launch_bounds__(256) void k_bprep(
        const unsigned int* __restrict__ ebuf, const int* __restrict__ meta,
        const float* __restrict__ x,
        float* __restrict__ dinv, unsigned short* __restrict__ xs,
        int* __restrict__ off, int* __restrict__ oend, int* __restrict__ srow,
        int n, int NBLK, int NBK) {
    __shared__ int h[256];
    __shared__ int cur[256];
    __shared__ int cnts[512];
    __shared__ int locs[512];
    __shared__ int scn[512];
    __shared__ unsigned stage[BSTAGE];   // 64 KB
    int t = threadIdx.x, b = blockIdx.x;
    int i0 = t, i1 = t + 256;
    h[t] = 0;
    cnts[i0] = 0; cnts[i1] = 0;
    __syncthreads();
    for (int k = t; k < NBLK; k += 256) {
        int m = meta[(size_t)k * NBK + b];
        cnts[k] = m & 0xffff;
        locs[k] = m >> 16;
    }
    __syncthreads();
    scn[i0] = cnts[i0]; scn[i1] = cnts[i1];
    __syncthreads();
    for (int d = 1; d < 512; d <<= 1) {
        int v0 = (i0 >= d) ? scn[i0 - d] : 0;
        int v1 = (i1 >= d) ? scn[i1 - d] : 0;
        __syncthreads();
        scn[i0] += v0; scn[i1] += v1;
        __syncthreads();
    }
    int mtot = scn[511];
    bool fit = (mtot <= BSTAGE);
    if (fit) {
        for (int k = t; k < NBLK; k += 256) {
            int cnt = cnts[k];
            const unsigned* src = ebuf + (size_t)k * EPB + locs[k];
            int dst = scn[k] - cnt;
            for (int q = 0; q < cnt; q++) {
                unsigned rec = src[q];
                stage[dst + q] = rec;
                atomicAdd(&h[rec & 255], 1);
            }
        }
    } else {
        for (int k = t; k < NBLK; k += 256) {
            int cnt = cnts[k];
            const unsigned* src = ebuf + (size_t)k * EPB + locs[k];
            for (int q = 0; q < cnt; q++)
                atomicAdd(&h[src[q] & 255], 1);
        }
    }
    __syncthreads();
    int dg = h[t];
    cur[t] = dg;
    __syncthreads();
    for (int d = 1; d < 256; d <<= 1) {
        int tmp = (t >= d) ? cur[t - d] : 0;
        __syncthreads();
        cur[t] += tmp;
        __syncthreads();
    }
    int base = b * SROWSTRIDE;
    int myoff = base + cur[t] - dg;   // exclusive offset in bucket's region
    int node = b * 256 + t;
    if (node < n) {
        off[node]  = myoff;
        oend[node] = myoff + dg;
        float d = rsqrtf((float)(dg + 1));
        dinv[node] = d;
        unsigned short r[8];
#pragma unroll
        for (int k = 0; k < 7; k++) r[k] = f2bf(x[(size_t)node * 7 + k] * d);
        r[7] = 0;
        uint4 v;
        v.x = (unsigned)r[0] | ((unsigned)r[1] << 16);
        v.y = (unsigned)r[2] | ((unsigned)r[3] << 16);
        v.z = (unsigned)r[4] | ((unsigned)r[5] << 16);
        v.w = (unsigned)r[6] | ((unsigned)r[7] << 16);
        *(uint4*)(xs + (size_t)node * 8) = v;
    }
    __syncthreads();
    cur[t] = myoff;                   // scatter cursors
    __syncthreads();
    if (fit) {
        for (int j = t; j < mtot; j += 256) {
            unsigned rec = stage[j];
            int p = atomicAdd(&cur[rec & 255], 1);
            srow[p] = (int)(rec >> 8);
        }
    } else {
        for (int k = t; k < NBLK; k += 256) {
            int cnt = cnts[k];
            const unsigned* src = ebuf + (size_t)k * EPB + locs[k];
            for (int q = 0; q < cnt; q++) {
                unsigned rec = src[q];
                int p = atomicAdd(&cur[rec & 255], 1);
                srow[p] = (int)(rec >> 8);
            }
        }
    }
}

// ---------------------------------------------------------------------------
// Layer-1 aggregation: QUAD per node. Lane fp owns 2 bf16 features; packed
// f32x2 accumulation; gather loop unrolled 8x (8 loads in flight per lane).
__global__ __launch_bounds__(256) void k_agg1(
        const unsigned short* __restrict__ xs, const float* __restrict__ dinv,
        const int* __restrict__ off, const int* __restrict__ oend,
        const int* __restrict__ srow, float* __restrict__ aggx, int n) {
    int tid = blockIdx.x * blockDim.x + threadIdx.x;
    int c = tid >> 2;
    if (c >= n) return;
    int fp = tid & 3;
    int o0 = off[c], o1 = oend[c];
    f32x2 A = {0.f, 0.f};
    auto addp = [&](unsigned u) {
        union { unsigned x; float f; } lo, hi;
        lo.x = u << 16;
        hi.x = u & 0xffff0000u;
        f32x2 v; v.x = lo.f; v.y = hi.f;
        A += v;
    };
    addp(*(const unsigned*)(xs + (size_t)c * 8 + fp * 2));   // self loop
    int j = o0;
    for (; j + 8 <= o1; j += 8) {
        int r0 = srow[j],     r1 = srow[j + 1], r2 = srow[j + 2], r3 = srow[j + 3];
        int r4 = srow[j + 4], r5 = srow[j + 5], r6 = srow[j + 6], r7 = srow[j + 7];
        unsigned u0 = *(const unsigned*)(xs + (size_t)r0 * 8 + fp * 2);
        unsigned u1 = *(const unsigned*)(xs + (size_t)r1 * 8 + fp * 2);
        unsigned u2 = *(const unsigned*)(xs + (size_t)r2 * 8 + fp * 2);
        unsigned u3 = *(const unsigned*)(xs + (size_t)r3 * 8 + fp * 2);
        unsigned u4 = *(const unsigned*)(xs + (size_t)r4 * 8 + fp * 2);
        unsigned u5 = *(const unsigned*)(xs + (size_t)r5 * 8 + fp * 2);
        unsigned u6 = *(const unsigned*)(xs + (size_t)r6 * 8 + fp * 2);
        unsigned u7 = *(const unsigned*)(xs + (size_t)r7 * 8 + fp * 2);
        addp(u0); addp(u1); addp(u2); addp(u3);
        addp(u4); addp(u5); addp(u6); addp(u7);
    }
    for (; j + 4 <= o1; j += 4) {
        int r0 = srow[j], r1 = srow[j + 1], r2 = srow[j + 2], r3 = srow[j + 3];
        unsigned u0 = *(const unsigned*)(xs + (size_t)r0 * 8 + fp * 2);
        unsigned u1 = *(const unsigned*)(xs + (size_t)r1 * 8 + fp * 2);
        unsigned u2 = *(const unsigned*)(xs + (size_t)r2 * 8 + fp * 2);
        unsigned u3 = *(const unsigned*)(xs + (size_t)r3 * 8 + fp * 2);
        addp(u0); addp(u1); addp(u2); addp(u3);
    }
    for (; j < o1; j++)
        addp(*(const unsigned*)(xs + (size_t)srow[j] * 8 + fp * 2));
    float d = dinv[c];
    aggx[(size_t)c * 8 + fp * 2]     = A.x * d;
    aggx[(size_t)c * 8 + fp * 2 + 1] = A.y * d;
}

// Per node: h1 = relu(aggx @ W1 + b1); hs = (h1 @ W2) * dinv encoded as
// fp8 e4m3 x8 scale (32B row) if available, else bf16 (64B row).
// Also computes gstart from sorted batch.
__global__ __launch_bounds__(256) void k_mlp1(
        const float* __restrict__ aggx, const float* __restrict__ dinv,
        const float* __restrict__ W1, const float* __restrict__ b1,
        const float* __restrict__ W2,
        unsigned int* __restrict__ hs,
        const int* __restrict__ batch, int* __restrict__ gstart, int n) {
    __shared__ float sW1[7 * 64];
    __shared__ float sb1[64];
    __shared__ float sW2[64 * 32];
    for (int t = threadIdx.x; t < 7 * 64; t += blockDim.x) sW1[t] = W1[t];
    for (int t = threadIdx.x; t < 64; t += blockDim.x) sb1[t] = b1[t];
    for (int t = threadIdx.x; t < 64 * 32; t += blockDim.x) sW2[t] = W2[t];
    __syncthreads();

    int i = blockIdx.x * blockDim.x + threadIdx.x;
    if (i >= n) return;

    {   // graph start offsets (sorted batch, empty-graph safe)
        int g = batch[i];
        int gp = (i == 0) ? -1 : batch[i - 1];
        for (int q = gp + 1; q <= g; q++) gstart[q] = i;
        if (i == n - 1)
            for (int q = g + 1; q <= N_GRAPHS; q++) gstart[q] = n;
    }

    float a[7];
#pragma unroll
    for (int k = 0; k < 7; k++) a[k] = aggx[(size_t)i * 8 + k];

    float acc[32];
#pragma unroll
    for (int m = 0; m < 32; m++) acc[m] = 0.f;

    for (int j = 0; j < 64; j++) {
        float v = sb1[j];
#pragma unroll
        for (int k = 0; k < 7; k++) v += a[k] * sW1[k * 64 + j];
        v = fmaxf(v, 0.f);  // relu(conv1)
#pragma unroll
        for (int m = 0; m < 32; m++) acc[m] += v * sW2[j * 32 + m];
    }
    float d = dinv[i];
#if HAS_FP8
    float sc = d * 8.f;                 // fp8 scale = 8
    unsigned w[8];
#pragma unroll
    for (int q = 0; q < 8; q++) {
        unsigned t0 = (unsigned)__builtin_amdgcn_cvt_pk_fp8_f32(
            acc[4 * q] * sc, acc[4 * q + 1] * sc, 0, false);
        w[q] = (unsigned)__builtin_amdgcn_cvt_pk_fp8_f32(
            acc[4 * q + 2] * sc, acc[4 * q + 3] * sc, (int)t0, true);
    }
    uint4* o = (uint4*)(hs + (size_t)i * 8);
    o[0] = make_uint4(w[0], w[1], w[2], w[3]);
    o[1] = make_uint4(w[4], w[5], w[6], w[7]);
#else
    unsigned up[16];
#pragma unroll
    for (int m = 0; m < 16; m++)
        up[m] = (unsigned)f2bf(acc[2 * m] * d) |
                ((unsigned)f2bf(acc[2 * m + 1] * d) << 16);
    uint4* o = (uint4*)(hs + (size_t)i * 16);
    o[0] = make_uint4(up[0],  up[1],  up[2],  up[3]);
    o[1] = make_uint4(up[4],  up[5],  up[6],  up[7]);
    o[2] = make_uint4(up[8],  up[9],  up[10], up[11]);
    o[3] = make_uint4(up[12], up[13], up[14], up[15]);
#endif
}

// Layer-2 aggregation: QUAD per node. Lane fp owns 8 fp8 features (uint2);
// packed f32x2 accumulation; gather loop unrolled 8x.
__global__ __launch_bounds__(256) void k_agg2(
        const unsigned int* __restrict__ hs, const float* __restrict__ dinv,
        const int* __restrict__ off, const int* __restrict__ oend,
        const int* __restrict__ srow, float* __restrict__ agg2, int n) {
    int tid = blockIdx.x * blockDim.x + threadIdx.x;
    int c = tid >> 2;
    if (c >= n) return;
    int fp = tid & 3;
    int o0 = off[c], o1 = oend[c];
#if HAS_FP8
    f32x2 A0 = {0.f, 0.f}, A1 = {0.f, 0.f}, A2 = {0.f, 0.f}, A3 = {0.f, 0.f};
    auto dec = [&](uint2 u) {
        A0 += __builtin_amdgcn_cvt_pk_f32_fp8((int)u.x, false);
        A1 += __builtin_amdgcn_cvt_pk_f32_fp8((int)u.x, true);
        A2 += __builtin_amdgcn_cvt_pk_f32_fp8((int)u.y, false);
        A3 += __builtin_amdgcn_cvt_pk_f32_fp8((int)u.y, true);
    };
    dec(*(const uint2*)(hs + (size_t)c * 8 + fp * 2));   // self loop
    int j = o0;
    for (; j + 8 <= o1; j += 8) {
        int r0 = srow[j],     r1 = srow[j + 1], r2 = srow[j + 2], r3 = srow[j + 3];
        int r4 = srow[j + 4], r5 = srow[j + 5], r6 = srow[j + 6], r7 = srow[j + 7];
        uint2 u0 = *(const uint2*)(hs + (size_t)r0 * 8 + fp * 2);
        uint2 u1 = *(const uint2*)(hs + (size_t)r1 * 8 + fp * 2);
        uint2 u2 = *(const uint2*)(hs + (size_t)r2 * 8 + fp * 2);
        uint2 u3 = *(const uint2*)(hs + (size_t)r3 * 8 + fp * 2);
        uint2 u4 = *(const uint2*)(hs + (size_t)r4 * 8 + fp * 2);
        uint2 u5 = *(const uint2*)(hs + (size_t)r5 * 8 + fp * 2);
        uint2 u6 = *(const uint2*)(hs + (size_t)r6 * 8 + fp * 2);
        uint2 u7 = *(const uint2*)(hs + (size_t)r7 * 8 + fp * 2);
        dec(u0); dec(u1); dec(u2); dec(u3);
        dec(u4); dec(u5); dec(u6); dec(u7);
    }
    for (; j + 4 <= o1; j += 4) {
        int r0 = srow[j], r1 = srow[j + 1], r2 = srow[j + 2], r3 = srow[j + 3];
        uint2 u0 = *(const uint2*)(hs + (size_t)r0 * 8 + fp * 2);
        uint2 u1 = *(const uint2*)(hs + (size_t)r1 * 8 + fp * 2);
        uint2 u2 = *(const uint2*)(hs + (size_t)r2 * 8 + fp * 2);
        uint2 u3 = *(const uint2*)(hs + (size_t)r3 * 8 + fp * 2);
        dec(u0); dec(u1); dec(u2); dec(u3);
    }
    for (; j < o1; j++)
        dec(*(const uint2*)(hs + (size_t)srow[j] * 8 + fp * 2));
    float d = dinv[c] * 0.125f;     // undo fp8 scale
    float4* o = (float4*)(agg2 + (size_t)c * 32 + fp * 8);
    o[0] = make_float4(A0.x * d, A0.y * d, A1.x * d, A1.y * d);
    o[1] = make_float4(A2.x * d, A2.y * d, A3.x * d, A3.y * d);
#else
    float a0 = 0.f, a1 = 0.f, a2 = 0.f, a3 = 0.f;
    float a4 = 0.f, a5 = 0.f, a6 = 0.f, a7 = 0.f;
    auto addpair = [&](float& x0, float& x1, unsigned u) {
        union { unsigned x; float f; } lo, hi;
        lo.x = u << 16; hi.x = u & 0xffff0000u;
        x0 += lo.f; x1 += hi.f;
    };
    auto dec = [&](uint4 u) {
        addpair(a0, a1, u.x); addpair(a2, a3, u.y);
        addpair(a4, a5, u.z); addpair(a6, a7, u.w);
    };
    dec(*(const uint4*)(hs + (size_t)c * 16 + fp * 4));  // self loop
    int j = o0;
    for (; j + 4 <= o1; j += 4) {
        int r0 = srow[j], r1 = srow[j + 1], r2 = srow[j + 2], r3 = srow[j + 3];
        uint4 u0 = *(const uint4*)(hs + (size_t)r0 * 16 + fp * 4);
        uint4 u1 = *(const uint4*)(hs + (size_t)r1 * 16 + fp * 4);
        uint4 u2 = *(const uint4*)(hs + (size_t)r2 * 16 + fp * 4);
        uint4 u3 = *(const uint4*)(hs + (size_t)r3 * 16 + fp * 4);
        dec(u0); dec(u1); dec(u2); dec(u3);
    }
    for (; j < o1; j++)
        dec(*(const uint4*)(hs + (size_t)srow[j] * 16 + fp * 4));
    float d = dinv[c];
    float4* o = (float4*)(agg2 + (size_t)c * 32 + fp * 8);
    o[0] = make_float4(a0 * d, a1 * d, a2 * d, a3 * d);
    o[1] = make_float4(a4 * d, a5 * d, a6 * d, a7 * d);
#endif
}

// ---------------------------------------------------------------------------
// Mean-pool partials: 8 chunk-blocks per graph; private slots, no atomics.
__global__ __launch_bounds__(256) void k_pool(
        const float* __restrict__ agg2, const float* __restrict__ b2,
        const int* __restrict__ gstart, float* __restrict__ psum) {
    int g = blockIdx.x >> 3, ch = blockIdx.x & 7;
    int s = gstart[g], e = gstart[g + 1];
    int cnt = e - s;
    int per = (cnt + 7) >> 3;
    int cs = s + ch * per, ce = min(e, cs + per);

    int t = threadIdx.x;
    int fq = t & 7, nl = t >> 3;
    const float4* b2q4 = (const float4*)b2;
    float4 bq = b2q4[fq];
    float4 acc = make_float4(0.f, 0.f, 0.f, 0.f);
    for (int i = cs + nl; i < ce; i += 32) {
        float4 v = *(const float4*)(agg2 + (size_t)i * 32 + fq * 4);
        acc.x += fmaxf(v.x + bq.x, 0.f);
        acc.y += fmaxf(v.y + bq.y, 0.f);
        acc.z += fmaxf(v.z + bq.z, 0.f);
        acc.w += fmaxf(v.w + bq.w, 0.f);
    }
#pragma unroll
    for (int m = 8; m < 64; m <<= 1) {
        acc.x += __shfl_xor(acc.x, m);
        acc.y += __shfl_xor(acc.y, m);
        acc.z += __shfl_xor(acc.z, m);
        acc.w += __shfl_xor(acc.w, m);
    }
    __shared__ float4 part[4][8];
    int w = t >> 6, lane = t & 63;
    if (lane < 8) part[w][lane] = acc;
    __syncthreads();
    if (t < 8) {
        float4 p0 = part[0][t], p1 = part[1][t], p2 = part[2][t], p3 = part[3][t];
        float4 r;
        r.x = p0.x + p1.x + p2.x + p3.x;
        r.y = p0.y + p1.y + p2.y + p3.y;
        r.z = p0.z + p1.z + p2.z + p3.z;
        r.w = p0.w + p1.w + p2.w + p3.w;
        *(float4*)(psum + ((size_t)((g << 3) + ch)) * 32 + t * 4) = r;
    }
}

// out[g][o] = (sum_m (sum_ch psum[g*8+ch][m]) * Wl[m][o]) / max(cnt,1) + bl[o]
__global__ void k_out(const float* __restrict__ psum, const int* __restrict__ gstart,
                      const float* __restrict__ Wl, const float* __restrict__ bl,
                      float* __restrict__ out) {
    int t = blockIdx.x * blockDim.x + threadIdx.x;
    if (t >= N_GRAPHS * 5) return;
    int g = t / 5, o = t % 5;
    float c = (float)max(gstart[g + 1] - gstart[g], 1);
    float acc = 0.f;
#pragma unroll
    for (int m = 0; m < 32; m++) {
        float s = 0.f;
#pragma unroll
        for (int ch = 0; ch < 8; ch++)
            s += psum[((size_t)((g << 3) + ch)) * 32 + m];
        acc += s * Wl[m * 5 + o];
    }
    out[t] = acc / c + bl[o];
}

extern "C" void kernel_launch(void* const* d_in, const int* in_sizes, int n_in,
                              void* d_out, int out_size, void* d_ws, size_t ws_size,
                              hipStream_t stream) {
    const float* x     = (const float*)d_in[0];
    const int*   ei    = (const int*)d_in[1];
    const int*   batch = (const int*)d_in[2];
    const float* W1    = (const float*)d_in[3];
    const float* b1    = (const float*)d_in[4];
    const float* W2    = (const float*)d_in[5];
    const float* b2    = (const float*)d_in[6];
    const float* Wl    = (const float*)d_in[7];
    const float* bl    = (const float*)d_in[8];
    float* out = (float*)d_out;

    const int n = in_sizes[0] / 7;        // 100000
    const int E = in_sizes[1] / 2;        // 3200000
    const int* row = ei;                  // edge_index[0]
    const int* col = ei + E;              // edge_index[1]

    const int NBK  = (n + 255) >> 8;              // 391 node-buckets
    const int NBLK = (E + EPB - 1) / EPB;         // 391 edge-chunks

    // workspace carve-up (256B aligned)
    char* p = (char*)d_ws;
    auto alloc = [&](size_t bytes) -> char* {
        char* r = p;
        p += (bytes + 255) & ~(size_t)255;
        return r;
    };
    int*   meta   = (int*)  alloc((size_t)NBLK * NBK * 4);          // 612 KB
    unsigned int* ebuf = (unsigned int*)alloc((size_t)E * 4);
    int*   srow   = (int*)  alloc((size_t)NBK * SROWSTRIDE * 4);    // 25.6 MB
    float* dinv   = (float*)alloc((size_t)n * 4);
    int*   off    = (int*)  alloc((size_t)n * 4);
    int*   oendv  = (int*)  alloc((size_t)n * 4);
    unsigned short* xs = (unsigned short*)alloc((size_t)n * 8 * 2);
    float* aggx   = (float*)alloc((size_t)n * 8 * 4);
    unsigned int* hs = (unsigned int*)alloc((size_t)n * 16 * 4);    // max (bf16) size
    float* agg2   = (float*)alloc((size_t)n * 32 * 4);
    int*   gstart = (int*)  alloc((N_GRAPHS + 1) * 4);
    float* psum   = (float*)alloc((size_t)N_GRAPHS * 8 * 32 * 4);

    const int BT = 256;
    int nb_n    = (n + BT - 1) / BT;
    int nb_quad = (n * 4 + BT - 1) / BT;          // one quad (4 lanes) per node

    // chunk-local binned CSR build (single edge read, fixed bucket regions)
    k_count2 <<<NBLK, BT, 0, stream>>>(row, col, meta, ebuf, E, NBLK, NBK);
    k_bprep  <<<NBK, BT, 0, stream>>>(ebuf, meta, x, dinv, xs, off, oendv, srow,
                                      n, NBLK, NBK);

    // GNN pipeline (quad-per-node gathers, packed-f32 accumulation, 8x unroll)
    k_agg1   <<<nb_quad, BT, 0, stream>>>(xs, dinv, off, oendv, srow, aggx, n);
    k_mlp1   <<<nb_n, BT, 0, stream>>>(aggx, dinv, W1, b1, W2, hs, batch, gstart, n);
    k_agg2   <<<nb_quad, BT, 0, stream>>>(hs, dinv, off, oendv, srow, agg2, n);
    k_pool   <<<N_GRAPHS * 8, BT, 0, stream>>>(agg2, b2, gstart, psum);
    k_out    <<<1, 320, 0, stream>>>(psum, gstart, Wl, bl, out);
}